// Round 1
// baseline (926.755 us; speedup 1.0000x reference)
//
#include <hip/hip_runtime.h>
#include <hip/hip_bf16.h>
#include <math.h>

// out = tanh(x @ (exp(s)[:,None] * V) + bias)
// BATCH=1048576, IN_DIM=128, UNITS=128, all fp32.
//
// Strategy: memory-bound streaming GEMM. x kept fp16 (RTN), W split into
// fp16 hi+lo (W exact to 2^-22), z = x16@Whi + x16@Wlo via
// mfma_f32_16x16x32_f16. Error budget ~5e-3 absmax vs 2e-2 threshold.
// B fragments live entirely in registers (128 VGPRs); no LDS, no barriers.

typedef _Float16 half8 __attribute__((ext_vector_type(8)));
typedef float float4v __attribute__((ext_vector_type(4)));

#define RWF_BATCH   1048576
#define RWF_K       128
#define RWF_N       128
#define RWF_TILE_M  64
#define RWF_NTILES  (RWF_BATCH / RWF_TILE_M)   // 16384
#define RWF_GRID    2048

// ---------------------------------------------------------------------------
// Setup: W = exp(s)[:,None] * V  -> transposed fp16 hi/lo in d_ws.
// ws layout (as _Float16*): [0,16384): wT_hi[n*128+k], [16384,32768): wT_lo.
// ---------------------------------------------------------------------------
__global__ void rwf_setup_w(const float* __restrict__ s,
                            const float* __restrict__ V,
                            _Float16* __restrict__ wsT) {
    int t = blockIdx.x * blockDim.x + threadIdx.x;   // 0..16383
    int i = t >> 7;     // k index (row of V / index into s)
    int j = t & 127;    // n index (col of V)
    float w = expf(s[i]) * V[t];
    _Float16 hi = (_Float16)w;                 // RTN
    _Float16 lo = (_Float16)(w - (float)hi);   // residual, also fp16
    wsT[j * 128 + i]         = hi;
    wsT[16384 + j * 128 + i] = lo;
}

// ---------------------------------------------------------------------------
// Main kernel. Block = 256 threads (4 waves). Block tile: 64 rows x 128 cols.
// Wave (w>>1) selects 32-row half, (w&1) selects 64-col half.
// Each wave: 2 m-tiles x 4 n-tiles of 16x16, K=128 in 4 MFMA k-steps.
// ---------------------------------------------------------------------------
__global__ __launch_bounds__(256, 2) void rwf_main(
    const float* __restrict__ x,
    const float* __restrict__ bias,
    const _Float16* __restrict__ wsT,
    float* __restrict__ out)
{
    const int lane = threadIdx.x & 63;
    const int wave = threadIdx.x >> 6;     // 0..3
    const int ln15 = lane & 15;
    const int quad = lane >> 4;            // 0..3

    const int wrow = (wave >> 1) * 32;     // row offset within 64-row tile
    const int wcol = (wave & 1) * 64;      // col offset within 128 cols

    // --- B fragments, held in registers for the whole kernel -------------
    // B-frag layout for 16x16x32: lane holds B[k = quad*8+j][n = ln15].
    // wsT is stored [n][k], so 8 consecutive k's = one 16B load.
    half8 bh[4][4], bl[4][4];   // [kstep][ntile]
    #pragma unroll
    for (int ks = 0; ks < 4; ++ks) {
        #pragma unroll
        for (int nt = 0; nt < 4; ++nt) {
            int n   = wcol + nt * 16 + ln15;
            int off = n * 128 + ks * 32 + quad * 8;
            bh[ks][nt] = *(const half8*)(wsT + off);
            bl[ks][nt] = *(const half8*)(wsT + 16384 + off);
        }
    }

    // bias per n-tile (col = wcol + nt*16 + ln15)
    float bv[4];
    #pragma unroll
    for (int nt = 0; nt < 4; ++nt) bv[nt] = bias[wcol + nt * 16 + ln15];

    for (int tile = blockIdx.x; tile < RWF_NTILES; tile += gridDim.x) {
        const int row0 = tile * RWF_TILE_M + wrow;

        float4v acc[2][4];
        #pragma unroll
        for (int mt = 0; mt < 2; ++mt)
            #pragma unroll
            for (int nt = 0; nt < 4; ++nt)
                acc[mt][nt] = (float4v)0.0f;

        #pragma unroll
        for (int ks = 0; ks < 4; ++ks) {
            // A-frag: lane holds x[row = mt*16+ln15][k = ks*32+quad*8+j],
            // 8 consecutive floats -> 2 x dwordx4, convert to fp16 RTN.
            half8 a[2];
            #pragma unroll
            for (int mt = 0; mt < 2; ++mt) {
                const float* p = x + (size_t)(row0 + mt * 16 + ln15) * RWF_K
                                   + ks * 32 + quad * 8;
                float4v u0 = *(const float4v*)p;
                float4v u1 = *(const float4v*)(p + 4);
                half8 av;
                av[0] = (_Float16)u0[0]; av[1] = (_Float16)u0[1];
                av[2] = (_Float16)u0[2]; av[3] = (_Float16)u0[3];
                av[4] = (_Float16)u1[0]; av[5] = (_Float16)u1[1];
                av[6] = (_Float16)u1[2]; av[7] = (_Float16)u1[3];
                a[mt] = av;
            }
            #pragma unroll
            for (int mt = 0; mt < 2; ++mt) {
                #pragma unroll
                for (int nt = 0; nt < 4; ++nt) {
                    acc[mt][nt] = __builtin_amdgcn_mfma_f32_16x16x32_f16(
                        a[mt], bh[ks][nt], acc[mt][nt], 0, 0, 0);
                    acc[mt][nt] = __builtin_amdgcn_mfma_f32_16x16x32_f16(
                        a[mt], bl[ks][nt], acc[mt][nt], 0, 0, 0);
                }
            }
        }

        // --- epilogue: bias + tanh + store -------------------------------
        // C/D layout: col = ln15, row = quad*4 + r  [m89-verified].
        #pragma unroll
        for (int mt = 0; mt < 2; ++mt) {
            #pragma unroll
            for (int nt = 0; nt < 4; ++nt) {
                #pragma unroll
                for (int r = 0; r < 4; ++r) {
                    int row = row0 + mt * 16 + quad * 4 + r;
                    int col = wcol + nt * 16 + ln15;
                    float z = acc[mt][nt][r] + bv[nt];
                    // tanh(z) = 1 - 2/(e^{2z}+1); saturates via inf math.
                    float e = __expf(2.0f * z);
                    float o = 1.0f - 2.0f * __builtin_amdgcn_rcpf(e + 1.0f);
                    out[(size_t)row * RWF_N + col] = o;
                }
            }
        }
    }
}

// ---------------------------------------------------------------------------
extern "C" void kernel_launch(void* const* d_in, const int* in_sizes, int n_in,
                              void* d_out, int out_size, void* d_ws, size_t ws_size,
                              hipStream_t stream) {
    const float* x    = (const float*)d_in[0];
    const float* s    = (const float*)d_in[1];
    const float* V    = (const float*)d_in[2];
    const float* bias = (const float*)d_in[3];
    float* out        = (float*)d_out;
    _Float16* wsT     = (_Float16*)d_ws;   // 32768 halves = 64 KiB

    // Setup runs every call: d_ws is re-poisoned before each timed launch.
    rwf_setup_w<<<(RWF_K * RWF_N) / 256, 256, 0, stream>>>(s, V, wsT);
    rwf_main<<<RWF_GRID, 256, 0, stream>>>(x, bias, wsT, out);
}